// Round 5
// baseline (690.668 us; speedup 1.0000x reference)
//
#include <hip/hip_runtime.h>
#include <stdint.h>

typedef unsigned short u16;
typedef __bf16 bf16x8 __attribute__((ext_vector_type(8)));
typedef float f32x4 __attribute__((ext_vector_type(4)));

#define MFMA16(a, b, c) __builtin_amdgcn_mfma_f32_16x16x32_bf16(a, b, c, 0, 0, 0)

// ---- problem constants ----
static constexpr int kC = 192;
static constexpr int kNH = 6;
static constexpr int kTok = 131072;          // B * T*H*W
static constexpr float kScale = 0.17677669529663687f;  // 32^-0.5

__device__ __forceinline__ float bf2f(u16 u) {
  union { uint32_t i; float f; } c; c.i = (uint32_t)u << 16; return c.f;
}
__device__ __forceinline__ u16 f2bf(float f) {
  union { float f; uint32_t i; } c; c.f = f;
  uint32_t r = c.i + 0x7fffu + ((c.i >> 16) & 1u);
  return (u16)(r >> 16);
}

// async global->LDS, 16B per lane; lds dest must be wave-uniform base (+lane*16 by HW)
__device__ __forceinline__ void gload_lds16(const void* g, void* l) {
  __builtin_amdgcn_global_load_lds((const __attribute__((address_space(1))) void*)g,
                                   (__attribute__((address_space(3))) void*)l, 16, 0, 0);
}

// shift-mask region code for (window-in-image, token-in-window), shifted coords
__device__ __forceinline__ int rcode(int widx, int n) {
  int t = ((widx >> 6) << 3) + (n >> 4);
  int h = (((widx >> 3) & 7) << 2) + ((n >> 2) & 3);
  int w = ((widx & 7) << 2) + (n & 3);
  int rt = (t < 56) ? 0 : ((t < 60) ? 1 : 2);
  int rh = (h < 28) ? 0 : ((h < 30) ? 1 : 2);
  int rw = (w < 28) ? 0 : ((w < 30) ? 1 : 2);
  return rt * 9 + rh * 3 + rw;
}

// window-row -> token index (window reverse + un-shift)
__device__ __forceinline__ long row2tok(int grow) {
  int bb = grow >> 16, widx = (grow >> 7) & 511, n = grow & 127;
  int tp = ((widx >> 6) << 3) + (n >> 4);
  int hp = (((widx >> 3) & 7) << 2) + ((n >> 2) & 3);
  int wp = ((widx & 7) << 2) + (n & 3);
  int tt = (tp + 4) & 63, hh2 = (hp + 2) & 31, ww2 = (wp + 2) & 31;
  return ((long)bb << 16) + (tt << 10) + (hh2 << 5) + ww2;
}

// ---- weight transpose + bf16 convert: Wt[n][k] = bf16(W[k][n])  (W fp32) ----
__global__ void transpose_kernel(const float* __restrict__ W, u16* __restrict__ Wt, int K, int Nd) {
  int idx = blockIdx.x * 256 + threadIdx.x;
  if (idx < K * Nd) {
    int n = idx / K;
    int k = idx - n * K;
    Wt[idx] = f2bf(W[(long)k * Nd + n]);
  }
}

// ---- exp(rel-pos-bias) table: EB[hh][n][m] = exp(rpb_table[relidx(n,m)][hh]) ----
// softmax(s + b) == (exp(s)*exp(b)) / sum(exp(s)*exp(b))  (shift-invariant; |s| << 80 here)
__global__ void ebias_kernel(const float* __restrict__ rpb, float* __restrict__ EB) {
  int idx = blockIdx.x * 256 + threadIdx.x;   // < 6*128*128 = 98304
  int hh = idx >> 14;
  int rem = idx & 16383;
  int n = rem >> 7, m = rem & 127;
  int tn = n >> 4, hn = (n >> 2) & 3, wn = n & 3;
  int tm = m >> 4, hm = (m >> 2) & 3, wm = m & 3;
  // faithful to reference: (dt+7)*15 + (dh+3)*7 + (dw+3)
  int ridx = (tn - tm + 7) * 15 + (hn - hm + 3) * 7 + (wn - wm + 3);
  EB[idx] = __expf(rpb[ridx * 6 + hh]);
}

// ---- LN1 + cyclic shift + window partition (fp32 in, bf16 out, permuted rows) ----
__global__ __launch_bounds__(256) void ln1_kernel(const float* __restrict__ x, const float* __restrict__ g,
                                                  const float* __restrict__ b, u16* __restrict__ xw) {
  int wv = threadIdx.x >> 6, lane = threadIdx.x & 63;
  int tok = blockIdx.x * 4 + wv;
  const float* xr = x + (long)tok * kC;
  float v0 = xr[lane], v1 = xr[lane + 64], v2 = xr[lane + 128];
  float s = v0 + v1 + v2;
  for (int m = 32; m; m >>= 1) s += __shfl_xor(s, m);
  float mu = s * (1.f / 192.f);
  float d0 = v0 - mu, d1 = v1 - mu, d2 = v2 - mu;
  float q = d0 * d0 + d1 * d1 + d2 * d2;
  for (int m = 32; m; m >>= 1) q += __shfl_xor(q, m);
  float rstd = rsqrtf(q * (1.f / 192.f) + 1e-5f);
  int bb = tok >> 16, loc = tok & 65535;
  int t = loc >> 10, h = (loc >> 5) & 31, w = loc & 31;
  int tp = (t + 60) & 63, hp = (h + 30) & 31, wp = (w + 30) & 31;
  int widx = ((tp >> 3) << 6) + ((hp >> 2) << 3) + (wp >> 2);
  int n = ((tp & 7) << 4) + ((hp & 3) << 2) + (wp & 3);
  long row = (((long)bb * 512 + widx) << 7) + n;
  u16* o = xw + row * kC;
  o[lane]       = f2bf(d0 * rstd * g[lane]       + b[lane]);
  o[lane + 64]  = f2bf(d1 * rstd * g[lane + 64]  + b[lane + 64]);
  o[lane + 128] = f2bf(d2 * rstd * g[lane + 128] + b[lane + 128]);
}

// ---- MFMA GEMM: 128x192 tile, 4 waves (2x2, each 64x96), gload_lds(16B), double-buffered ----
// out[M][ND] = A[M][K] @ Wt[ND][K]^T + bias(fp32), with epilogues.
// ND % 192 == 0 (exact column tiling, no masking); M % 128 == 0.
// EPI 0: store bf16; nb==0 (q columns) scaled by kScale              (qkv)
// EPI 1 (requires grid nb==1): + gather resid(fp32, token order), store bf16 x1 (window order)
//        AND fused LN2 -> store bf16 xm (window order)               (proj)
// EPI 2: erf-GELU, store bf16                                        (fc1)
// EPI 3: + x1w(bf16, window order), SCATTER-store fp32 token order   (fc2 -> d_out)
template <int K, int ND, int EPI>
__global__ __launch_bounds__(256, 3)
void gemm_kernel(const u16* __restrict__ A, const u16* __restrict__ Wt,
                 const float* __restrict__ bias, void* __restrict__ outp,
                 const float* __restrict__ resid, const u16* __restrict__ x1,
                 const float* __restrict__ g2, const float* __restrict__ b2,
                 u16* __restrict__ xmout) {
  static_assert(K % 32 == 0 && ND % 192 == 0, "tiling");
  constexpr int BM = 128, BN = 192;
  constexpr int ROWS = BM + BN;        // 320 rows of 32 bf16 (64 B) each
  constexpr int NT = K / 32;

  __shared__ u16 lds[2][ROWS * 32];    // 2 x 20 KB

  const int t = threadIdx.x;
  const int nb = blockIdx.x, mb = blockIdx.y;
  const int lane = t & 63, wv = t >> 6;
  const int wy = wv >> 1, wx = wv & 1;      // wave grid 2 (M) x 2 (N); per-wave 64x96
  const int quad = lane >> 4, l15 = lane & 15;

  f32x4 acc[4][6];
#pragma unroll
  for (int i = 0; i < 4; i++)
#pragma unroll
    for (int j = 0; j < 6; j++) acc[i][j] = (f32x4){0.f, 0.f, 0.f, 0.f};

  // staging: wave wv stages row-groups rr = wv, wv+4, ..., wv+16 (RG=20 exact)
  const u16* sp[5];
#pragma unroll
  for (int ii = 0; ii < 5; ii++) {
    int rr = wv + ii * 4;
    int row = rr * 16 + (lane >> 2);
    int c = (lane & 3) * 8;
    sp[ii] = (row < BM) ? A + (long)(mb * BM + row) * K + c
                        : Wt + (long)(nb * BN + (row - BM)) * K + c;
  }

  auto stage = [&](int buf, int k0) {
    u16* lb = &lds[buf][0];
#pragma unroll
    for (int ii = 0; ii < 5; ii++) {
      int rr = wv + ii * 4;
      gload_lds16(sp[ii] + k0, lb + rr * 512);
    }
  };

  stage(0, 0);
  __syncthreads();

  int buf = 0;
  for (int tt = 0; tt < NT; ++tt) {
    if (tt + 1 < NT) stage(buf ^ 1, (tt + 1) * 32);   // issue prefetch BEFORE compute
    const u16* lb = &lds[buf][0];
    bf16x8 af[4], bfr[6];
#pragma unroll
    for (int i = 0; i < 4; i++)
      af[i] = *(const bf16x8*)&lb[(wy * 64 + i * 16 + l15) * 32 + quad * 8];
#pragma unroll
    for (int j = 0; j < 6; j++)
      bfr[j] = *(const bf16x8*)&lb[(BM + wx * 96 + j * 16 + l15) * 32 + quad * 8];
#pragma unroll
    for (int i = 0; i < 4; i++)
#pragma unroll
      for (int j = 0; j < 6; j++) acc[i][j] = MFMA16(af[i], bfr[j], acc[i][j]);
    __syncthreads();   // drains vmcnt -> next buffer ready; frees this buffer for restage
    buf ^= 1;
  }

  // ---- epilogue ----
  float bcol[6];
#pragma unroll
  for (int j = 0; j < 6; j++) bcol[j] = bias[nb * BN + wx * 96 + j * 16 + l15];

  if constexpr (EPI == 1) {
    // proj + residual + fused LN2.  Requires gridDim.x == 1 (full 192-wide rows per block).
    float* partS = (float*)&lds[0][0];      // [128][2]
    float* partQ = partS + 256;             // [128][2]
    float g2c[6], b2c[6];
#pragma unroll
    for (int j = 0; j < 6; j++) {
      g2c[j] = g2[wx * 96 + j * 16 + l15];
      b2c[j] = b2[wx * 96 + j * 16 + l15];
    }
    float s1a[4][4], s2a[4][4];
#pragma unroll
    for (int i = 0; i < 4; i++) {
#pragma unroll
      for (int r = 0; r < 4; r++) {
        const int lrow = wy * 64 + i * 16 + quad * 4 + r;
        const long tokoff = row2tok(mb * BM + lrow) * 192;
        float s1 = 0.f, s2 = 0.f;
#pragma unroll
        for (int j = 0; j < 6; j++) {
          const int gcol = wx * 96 + j * 16 + l15;
          float v = acc[i][j][r] + bcol[j] + resid[tokoff + gcol];
          acc[i][j][r] = v;
          s1 += v; s2 += v * v;
        }
        s1 += __shfl_xor(s1, 1); s1 += __shfl_xor(s1, 2); s1 += __shfl_xor(s1, 4); s1 += __shfl_xor(s1, 8);
        s2 += __shfl_xor(s2, 1); s2 += __shfl_xor(s2, 2); s2 += __shfl_xor(s2, 4); s2 += __shfl_xor(s2, 8);
        if (l15 == 0) { partS[lrow * 2 + wx] = s1; partQ[lrow * 2 + wx] = s2; }
        s1a[i][r] = s1; s2a[i][r] = s2;
      }
    }
    __syncthreads();
#pragma unroll
    for (int i = 0; i < 4; i++) {
#pragma unroll
      for (int r = 0; r < 4; r++) {
        const int lrow = wy * 64 + i * 16 + quad * 4 + r;
        const long grow = mb * BM + lrow;
        float ts = s1a[i][r] + partS[lrow * 2 + (wx ^ 1)];
        float tq = s2a[i][r] + partQ[lrow * 2 + (wx ^ 1)];
        float mu = ts * (1.f / 192.f);
        float rstd = rsqrtf(tq * (1.f / 192.f) - mu * mu + 1e-5f);
#pragma unroll
        for (int j = 0; j < 6; j++) {
          const int gcol = wx * 96 + j * 16 + l15;
          float v = acc[i][j][r];
          ((u16*)outp)[grow * 192 + gcol] = f2bf(v);
          xmout[grow * 192 + gcol] = f2bf((v - mu) * rstd * g2c[j] + b2c[j]);
        }
      }
    }
    return;
  }

  const float qs = (EPI == 0 && nb == 0) ? kScale : 1.f;   // fold q scaling into qkv epilogue
#pragma unroll
  for (int i = 0; i < 4; i++) {
#pragma unroll
    for (int r = 0; r < 4; r++) {
      const int grow = mb * BM + wy * 64 + i * 16 + quad * 4 + r;
      long tokoff = 0;
      if constexpr (EPI == 3) tokoff = row2tok(grow) * 192;
#pragma unroll
      for (int j = 0; j < 6; j++) {
        const int gcol = nb * BN + wx * 96 + j * 16 + l15;
        float v = acc[i][j][r] + bcol[j];
        if constexpr (EPI == 0) {
          ((u16*)outp)[(long)grow * ND + gcol] = f2bf(v * qs);
        } else if constexpr (EPI == 2) {
          float gel = 0.5f * v * (1.0f + erff(v * 0.70710678118654752f));
          ((u16*)outp)[(long)grow * ND + gcol] = f2bf(gel);
        } else {
          ((float*)outp)[tokoff + gcol] = v + bf2f(x1[(long)grow * 192 + gcol]);
        }
      }
    }
  }
}

// ---- windowed MFMA attention: one block per (window, head) ----
// Q pre-scaled at qkv epilogue.  p = exp(s)*EB (no max-sub: |s| << 80), pre-normalized before PV.
__global__ __launch_bounds__(256, 3)
void attn_kernel(const u16* __restrict__ qkv, const float* __restrict__ EB, u16* __restrict__ attno) {
  __shared__ u16 uQK[17408];     // Qs[128*40] | Ks[128*40], later reused as Ps[128*136]
  __shared__ u16 Vt[32 * 136];   // V transposed [d][m]

  const int bid = blockIdx.x;
  const int wi = bid / kNH;           // global window 0..1023
  const int hh = bid - wi * kNH;      // head
  const int widx = wi & 511;          // window within image
  const int t = threadIdx.x;
  const int lane = t & 63, wv = t >> 6;
  const int quad = lane >> 4, l15 = lane & 15;

  {  // stage Q, K, V^T
    const int rr = t >> 1, half = (t & 1) * 16;
    const long base = (long)(wi * 128 + rr) * 576 + hh * 32 + half;
    uint4 q0 = *(const uint4*)(qkv + base);
    uint4 q1 = *(const uint4*)(qkv + base + 8);
    uint4 k0 = *(const uint4*)(qkv + base + 192);
    uint4 k1 = *(const uint4*)(qkv + base + 200);
    union { uint4 q[2]; u16 s[16]; } vv;
    vv.q[0] = *(const uint4*)(qkv + base + 384);
    vv.q[1] = *(const uint4*)(qkv + base + 392);
    u16* Qs = uQK;
    u16* Ks = uQK + 5120;
    *(uint4*)&Qs[rr * 40 + half] = q0;
    *(uint4*)&Qs[rr * 40 + half + 8] = q1;
    *(uint4*)&Ks[rr * 40 + half] = k0;
    *(uint4*)&Ks[rr * 40 + half + 8] = k1;
#pragma unroll
    for (int c = 0; c < 16; c++) Vt[(half + c) * 136 + rr] = vv.s[c];
  }
  __syncthreads();

  // S = Q K^T : each wave does rows [wv*32, wv*32+32) x 128 cols
  f32x4 sacc[2][8];
#pragma unroll
  for (int i = 0; i < 2; i++)
#pragma unroll
    for (int j = 0; j < 8; j++) sacc[i][j] = (f32x4){0.f, 0.f, 0.f, 0.f};
  {
    const u16* Qs = uQK;
    const u16* Ks = uQK + 5120;
    bf16x8 aq[2];
#pragma unroll
    for (int i = 0; i < 2; i++) aq[i] = *(const bf16x8*)&Qs[(wv * 32 + i * 16 + l15) * 40 + quad * 8];
    __builtin_amdgcn_s_setprio(1);
#pragma unroll
    for (int j = 0; j < 8; j++) {
      bf16x8 bk = *(const bf16x8*)&Ks[(j * 16 + l15) * 40 + quad * 8];
      sacc[0][j] = MFMA16(aq[0], bk, sacc[0][j]);
      sacc[1][j] = MFMA16(aq[1], bk, sacc[1][j]);
    }
    __builtin_amdgcn_s_setprio(0);
  }
  __syncthreads();  // all waves done with Qs/Ks; region becomes Ps

  // p = exp(s) * EB * maskbit, row-normalized, -> LDS bf16
  u16* Ps = uQK;  // [128][136]
  int ccnt[8];
#pragma unroll
  for (int j = 0; j < 8; j++) ccnt[j] = rcode(widx, j * 16 + l15);
  const float* EBh = EB + (hh << 14) + l15;
#pragma unroll
  for (int i = 0; i < 2; i++) {
#pragma unroll
    for (int r = 0; r < 4; r++) {
      int n = wv * 32 + i * 16 + quad * 4 + r;
      int rc = rcode(widx, n);
      const float* ebr = EBh + (n << 7);
      float pv[8];
      float l = 0.f;
#pragma unroll
      for (int j = 0; j < 8; j++) {
        float eb = ebr[j * 16];
        eb = (rc == ccnt[j]) ? eb : 0.f;
        float p = __expf(sacc[i][j][r]) * eb;
        pv[j] = p;
        l += p;
      }
      l += __shfl_xor(l, 1);
      l += __shfl_xor(l, 2);
      l += __shfl_xor(l, 4);
      l += __shfl_xor(l, 8);
      float rl = 1.f / l;
#pragma unroll
      for (int j = 0; j < 8; j++) Ps[n * 136 + j * 16 + l15] = f2bf(pv[j] * rl);
    }
  }
  __syncthreads();

  // O = P V : rows [wv*32, +32) x 32 cols
  f32x4 oacc[2][2];
#pragma unroll
  for (int i = 0; i < 2; i++)
#pragma unroll
    for (int j = 0; j < 2; j++) oacc[i][j] = (f32x4){0.f, 0.f, 0.f, 0.f};
  __builtin_amdgcn_s_setprio(1);
#pragma unroll
  for (int mc = 0; mc < 4; mc++) {
    bf16x8 ap[2], bv[2];
#pragma unroll
    for (int i = 0; i < 2; i++) ap[i] = *(const bf16x8*)&Ps[(wv * 32 + i * 16 + l15) * 136 + mc * 32 + quad * 8];
#pragma unroll
    for (int jj = 0; jj < 2; jj++) bv[jj] = *(const bf16x8*)&Vt[(jj * 16 + l15) * 136 + mc * 32 + quad * 8];
#pragma unroll
    for (int i = 0; i < 2; i++)
#pragma unroll
      for (int jj = 0; jj < 2; jj++) oacc[i][jj] = MFMA16(ap[i], bv[jj], oacc[i][jj]);
  }
  __builtin_amdgcn_s_setprio(0);
#pragma unroll
  for (int i = 0; i < 2; i++) {
#pragma unroll
    for (int jj = 0; jj < 2; jj++) {
#pragma unroll
      for (int r = 0; r < 4; r++) {
        int n = wv * 32 + i * 16 + quad * 4 + r;
        int d = jj * 16 + l15;
        attno[(long)(wi * 128 + n) * 192 + hh * 32 + d] = f2bf(oacc[i][jj][r]);
      }
    }
  }
}

extern "C" void kernel_launch(void* const* d_in, const int* in_sizes, int n_in,
                              void* d_out, int out_size, void* d_ws, size_t ws_size,
                              hipStream_t stream) {
  const float* x      = (const float*)d_in[0];
  const float* n1g    = (const float*)d_in[1];
  const float* n1b    = (const float*)d_in[2];
  const float* qkv_w  = (const float*)d_in[3];
  const float* qkv_b  = (const float*)d_in[4];
  const float* rpb    = (const float*)d_in[5];
  const float* proj_w = (const float*)d_in[6];
  const float* proj_b = (const float*)d_in[7];
  const float* n2g    = (const float*)d_in[8];
  const float* n2b    = (const float*)d_in[9];
  const float* fc1_w  = (const float*)d_in[10];
  const float* fc1_b  = (const float*)d_in[11];
  const float* fc2_w  = (const float*)d_in[12];
  const float* fc2_b  = (const float*)d_in[13];

  char* ws = (char*)d_ws;
  size_t off = 0;
  auto alloc = [&](size_t bytes) -> void* {
    void* p = ws + off;
    off += (bytes + 255) & ~(size_t)255;
    return p;
  };
  // lifetimes: xw: LN1out -> qkv; reused as attno (attn -> proj), reused as xm (LN2 -> fc1)
  //            qkvb: qkv (576 cols) -> attn; reused as fc1out (768 cols) -> fc2
  //            x1: residual stream bf16 in WINDOW order (proj out) -> fc2 epilogue.
  u16* WtQKV  = (u16*)alloc((size_t)110592 * 2);
  u16* WtPROJ = (u16*)alloc((size_t)36864 * 2);
  u16* WtFC1  = (u16*)alloc((size_t)147456 * 2);
  u16* WtFC2  = (u16*)alloc((size_t)147456 * 2);
  float* EB   = (float*)alloc((size_t)98304 * 4);   // exp(rel-pos-bias) [6][128][128]
  u16* xw     = (u16*)alloc((size_t)kTok * 192 * 2);
  u16* qkvb   = (u16*)alloc((size_t)kTok * 768 * 2);
  u16* x1     = (u16*)alloc((size_t)kTok * 192 * 2);
  u16* attno  = xw;
  u16* xm     = xw;

  transpose_kernel<<<(110592 + 255) / 256, 256, 0, stream>>>(qkv_w, WtQKV, 192, 576);
  transpose_kernel<<<(36864 + 255) / 256, 256, 0, stream>>>(proj_w, WtPROJ, 192, 192);
  transpose_kernel<<<(147456 + 255) / 256, 256, 0, stream>>>(fc1_w, WtFC1, 192, 768);
  transpose_kernel<<<(147456 + 255) / 256, 256, 0, stream>>>(fc2_w, WtFC2, 768, 192);
  ebias_kernel<<<98304 / 256, 256, 0, stream>>>(rpb, EB);

  ln1_kernel<<<kTok / 4, 256, 0, stream>>>(x, n1g, n1b, xw);
  // QKV: N=576 = 3 x 192 exact; q columns (nb==0) pre-scaled
  gemm_kernel<192, 576, 0><<<dim3(3, kTok / 128), 256, 0, stream>>>(xw, WtQKV, qkv_b, qkvb, nullptr, nullptr, nullptr, nullptr, nullptr);
  attn_kernel<<<1024 * kNH, 256, 0, stream>>>(qkvb, EB, attno);
  // proj: N=192, nb=1; gather resid (token order), write x1 + fused-LN2 xm (window order)
  gemm_kernel<192, 192, 1><<<dim3(1, kTok / 128), 256, 0, stream>>>(attno, WtPROJ, proj_b, x1, x, nullptr, n2g, n2b, xm);
  // fc1: N=768 = 4 x 192 exact
  gemm_kernel<192, 768, 2><<<dim3(4, kTok / 128), 256, 0, stream>>>(xm, WtFC1, fc1_b, qkvb, nullptr, nullptr, nullptr, nullptr, nullptr);
  // fc2: N=192, nb=1; scatter final fp32 out to token order
  gemm_kernel<768, 192, 3><<<dim3(1, kTok / 128), 256, 0, stream>>>(qkvb, WtFC2, fc2_b, d_out, nullptr, x1, nullptr, nullptr, nullptr);
}

// Round 6
// 580.611 us; speedup vs baseline: 1.1896x; 1.1896x over previous
//
#include <hip/hip_runtime.h>
#include <stdint.h>

typedef unsigned short u16;
typedef __bf16 bf16x8 __attribute__((ext_vector_type(8)));
typedef float f32x4 __attribute__((ext_vector_type(4)));

#define MFMA16(a, b, c) __builtin_amdgcn_mfma_f32_16x16x32_bf16(a, b, c, 0, 0, 0)

// ---- problem constants ----
static constexpr int kC = 192;
static constexpr int kNH = 6;
static constexpr int kTok = 131072;          // B * T*H*W
static constexpr float kScale = 0.17677669529663687f;  // 32^-0.5

__device__ __forceinline__ float bf2f(u16 u) {
  union { uint32_t i; float f; } c; c.i = (uint32_t)u << 16; return c.f;
}
__device__ __forceinline__ u16 f2bf(float f) {
  union { float f; uint32_t i; } c; c.f = f;
  uint32_t r = c.i + 0x7fffu + ((c.i >> 16) & 1u);
  return (u16)(r >> 16);
}

// async global->LDS, 16B per lane; lds dest must be wave-uniform base (+lane*16 by HW)
__device__ __forceinline__ void gload_lds16(const void* g, void* l) {
  __builtin_amdgcn_global_load_lds((const __attribute__((address_space(1))) void*)g,
                                   (__attribute__((address_space(3))) void*)l, 16, 0, 0);
}

// shift-mask region code for (window-in-image, token-in-window), shifted coords
__device__ __forceinline__ int rcode(int widx, int n) {
  int t = ((widx >> 6) << 3) + (n >> 4);
  int h = (((widx >> 3) & 7) << 2) + ((n >> 2) & 3);
  int w = ((widx & 7) << 2) + (n & 3);
  int rt = (t < 56) ? 0 : ((t < 60) ? 1 : 2);
  int rh = (h < 28) ? 0 : ((h < 30) ? 1 : 2);
  int rw = (w < 28) ? 0 : ((w < 30) ? 1 : 2);
  return rt * 9 + rh * 3 + rw;
}

// window-row -> token index (window reverse + un-shift)
__device__ __forceinline__ long row2tok(int grow) {
  int bb = grow >> 16, widx = (grow >> 7) & 511, n = grow & 127;
  int tp = ((widx >> 6) << 3) + (n >> 4);
  int hp = (((widx >> 3) & 7) << 2) + ((n >> 2) & 3);
  int wp = ((widx & 7) << 2) + (n & 3);
  int tt = (tp + 4) & 63, hh2 = (hp + 2) & 31, ww2 = (wp + 2) & 31;
  return ((long)bb << 16) + (tt << 10) + (hh2 << 5) + ww2;
}

// ---- weight transpose + bf16 convert: Wt[n][k] = bf16(W[k][n])  (W fp32) ----
__global__ void transpose_kernel(const float* __restrict__ W, u16* __restrict__ Wt, int K, int Nd) {
  int idx = blockIdx.x * 256 + threadIdx.x;
  if (idx < K * Nd) {
    int n = idx / K;
    int k = idx - n * K;
    Wt[idx] = f2bf(W[(long)k * Nd + n]);
  }
}

// ---- exp(rel-pos-bias) table: EB[hh][n][m] = exp(rpb_table[relidx(n,m)][hh]) ----
// softmax(s + b) == (exp(s)*exp(b)) / sum(exp(s)*exp(b))  (shift-invariant; |s| << 80 here)
__global__ void ebias_kernel(const float* __restrict__ rpb, float* __restrict__ EB) {
  int idx = blockIdx.x * 256 + threadIdx.x;   // < 6*128*128 = 98304
  int hh = idx >> 14;
  int rem = idx & 16383;
  int n = rem >> 7, m = rem & 127;
  int tn = n >> 4, hn = (n >> 2) & 3, wn = n & 3;
  int tm = m >> 4, hm = (m >> 2) & 3, wm = m & 3;
  // faithful to reference: (dt+7)*15 + (dh+3)*7 + (dw+3)
  int ridx = (tn - tm + 7) * 15 + (hn - hm + 3) * 7 + (wn - wm + 3);
  EB[idx] = __expf(rpb[ridx * 6 + hh]);
}

// ---- LN1 + cyclic shift + window partition (fp32 in, bf16 out, permuted rows) ----
__global__ __launch_bounds__(256) void ln1_kernel(const float* __restrict__ x, const float* __restrict__ g,
                                                  const float* __restrict__ b, u16* __restrict__ xw) {
  int wv = threadIdx.x >> 6, lane = threadIdx.x & 63;
  int tok = blockIdx.x * 4 + wv;
  const float* xr = x + (long)tok * kC;
  float v0 = xr[lane], v1 = xr[lane + 64], v2 = xr[lane + 128];
  float s = v0 + v1 + v2;
  for (int m = 32; m; m >>= 1) s += __shfl_xor(s, m);
  float mu = s * (1.f / 192.f);
  float d0 = v0 - mu, d1 = v1 - mu, d2 = v2 - mu;
  float q = d0 * d0 + d1 * d1 + d2 * d2;
  for (int m = 32; m; m >>= 1) q += __shfl_xor(q, m);
  float rstd = rsqrtf(q * (1.f / 192.f) + 1e-5f);
  int bb = tok >> 16, loc = tok & 65535;
  int t = loc >> 10, h = (loc >> 5) & 31, w = loc & 31;
  int tp = (t + 60) & 63, hp = (h + 30) & 31, wp = (w + 30) & 31;
  int widx = ((tp >> 3) << 6) + ((hp >> 2) << 3) + (wp >> 2);
  int n = ((tp & 7) << 4) + ((hp & 3) << 2) + (wp & 3);
  long row = (((long)bb * 512 + widx) << 7) + n;
  u16* o = xw + row * kC;
  o[lane]       = f2bf(d0 * rstd * g[lane]       + b[lane]);
  o[lane + 64]  = f2bf(d1 * rstd * g[lane + 64]  + b[lane + 64]);
  o[lane + 128] = f2bf(d2 * rstd * g[lane + 128] + b[lane + 128]);
}

// ---- MFMA GEMM: 128x192 tile, 8 waves (2M x 4N, each 64x48), gload_lds(16B), double-buffered ----
// acc[4][3] = 48 AGPR; total regs capped <=128 via __launch_bounds__(512,4) -> 16 waves/CU (2 blocks).
// out[M][ND] = A[M][K] @ Wt[ND][K]^T + bias(fp32), with epilogues.
// ND % 192 == 0 (exact column tiling, no masking); M % 128 == 0.
// EPI 0: store bf16; nb==0 (q columns) scaled by kScale              (qkv)
// EPI 1 (requires grid nb==1): + gather resid(fp32, token order), store bf16 x1 (window order)
//        AND fused LN2 -> store bf16 xm (window order)               (proj)
// EPI 2: erf-GELU, store bf16                                        (fc1)
// EPI 3: + x1w(bf16, window order), SCATTER-store fp32 token order   (fc2 -> d_out)
template <int K, int ND, int EPI>
__global__ __launch_bounds__(512, 4)
void gemm_kernel(const u16* __restrict__ A, const u16* __restrict__ Wt,
                 const float* __restrict__ bias, void* __restrict__ outp,
                 const float* __restrict__ resid, const u16* __restrict__ x1,
                 const float* __restrict__ g2, const float* __restrict__ b2,
                 u16* __restrict__ xmout) {
  static_assert(K % 32 == 0 && ND % 192 == 0, "tiling");
  constexpr int BM = 128, BN = 192;
  constexpr int ROWS = BM + BN;        // 320 rows of 32 bf16 (64 B) each
  constexpr int RG = ROWS / 16;        // 20 row-groups (1 KB each)
  constexpr int NT = K / 32;

  __shared__ u16 lds[2][ROWS * 32];    // 2 x 20 KB

  const int t = threadIdx.x;
  const int nb = blockIdx.x, mb = blockIdx.y;
  const int lane = t & 63, wv = t >> 6;
  const int wy = wv >> 2, wx = wv & 3;      // wave grid 2 (M) x 4 (N); per-wave 64x48
  const int quad = lane >> 4, l15 = lane & 15;

  f32x4 acc[4][3];
#pragma unroll
  for (int i = 0; i < 4; i++)
#pragma unroll
    for (int j = 0; j < 3; j++) acc[i][j] = (f32x4){0.f, 0.f, 0.f, 0.f};

  // staging: wave wv stages row-groups rr = wv, wv+8, wv+16 (rr < 20)
  const u16* sp[3];
#pragma unroll
  for (int ii = 0; ii < 3; ii++) {
    int rr = wv + ii * 8;
    if (rr < RG) {
      int row = rr * 16 + (lane >> 2);
      int c = (lane & 3) * 8;
      sp[ii] = (row < BM) ? A + (long)(mb * BM + row) * K + c
                          : Wt + (long)(nb * BN + (row - BM)) * K + c;
    } else {
      sp[ii] = nullptr;
    }
  }

  auto stage = [&](int buf, int k0) {
    u16* lb = &lds[buf][0];
#pragma unroll
    for (int ii = 0; ii < 3; ii++) {
      int rr = wv + ii * 8;
      if (rr < RG) gload_lds16(sp[ii] + k0, lb + rr * 512);
    }
  };

  stage(0, 0);
  __syncthreads();

  int buf = 0;
  for (int tt = 0; tt < NT; ++tt) {
    if (tt + 1 < NT) stage(buf ^ 1, (tt + 1) * 32);   // issue prefetch BEFORE compute
    const u16* lb = &lds[buf][0];
    bf16x8 af[4], bfr[3];
#pragma unroll
    for (int i = 0; i < 4; i++)
      af[i] = *(const bf16x8*)&lb[(wy * 64 + i * 16 + l15) * 32 + quad * 8];
#pragma unroll
    for (int j = 0; j < 3; j++)
      bfr[j] = *(const bf16x8*)&lb[(BM + wx * 48 + j * 16 + l15) * 32 + quad * 8];
#pragma unroll
    for (int i = 0; i < 4; i++)
#pragma unroll
      for (int j = 0; j < 3; j++) acc[i][j] = MFMA16(af[i], bfr[j], acc[i][j]);
    __syncthreads();   // drains vmcnt -> next buffer ready; frees this buffer for restage
    buf ^= 1;
  }

  // ---- epilogue ----
  float bcol[3];
#pragma unroll
  for (int j = 0; j < 3; j++) bcol[j] = bias[nb * BN + wx * 48 + j * 16 + l15];

  if constexpr (EPI == 1) {
    // proj + residual + fused LN2.  Requires gridDim.x == 1 (full 192-wide rows per block).
    float* partS = (float*)&lds[0][0];      // [128][4]
    float* partQ = partS + 512;             // [128][4]
    float g2c[3], b2c[3];
#pragma unroll
    for (int j = 0; j < 3; j++) {
      g2c[j] = g2[wx * 48 + j * 16 + l15];
      b2c[j] = b2[wx * 48 + j * 16 + l15];
    }
#pragma unroll
    for (int i = 0; i < 4; i++) {
#pragma unroll
      for (int r = 0; r < 4; r++) {
        const int lrow = wy * 64 + i * 16 + quad * 4 + r;
        const long tokoff = row2tok(mb * BM + lrow) * 192;
        float s1 = 0.f, s2 = 0.f;
#pragma unroll
        for (int j = 0; j < 3; j++) {
          const int gcol = wx * 48 + j * 16 + l15;
          float v = acc[i][j][r] + bcol[j] + resid[tokoff + gcol];
          acc[i][j][r] = v;
          s1 += v; s2 += v * v;
        }
        s1 += __shfl_xor(s1, 1); s1 += __shfl_xor(s1, 2); s1 += __shfl_xor(s1, 4); s1 += __shfl_xor(s1, 8);
        s2 += __shfl_xor(s2, 1); s2 += __shfl_xor(s2, 2); s2 += __shfl_xor(s2, 4); s2 += __shfl_xor(s2, 8);
        if (l15 == 0) { partS[lrow * 4 + wx] = s1; partQ[lrow * 4 + wx] = s2; }
      }
    }
    __syncthreads();
#pragma unroll
    for (int i = 0; i < 4; i++) {
#pragma unroll
      for (int r = 0; r < 4; r++) {
        const int lrow = wy * 64 + i * 16 + quad * 4 + r;
        const long grow = mb * BM + lrow;
        float ts = partS[lrow * 4 + 0] + partS[lrow * 4 + 1] + partS[lrow * 4 + 2] + partS[lrow * 4 + 3];
        float tq = partQ[lrow * 4 + 0] + partQ[lrow * 4 + 1] + partQ[lrow * 4 + 2] + partQ[lrow * 4 + 3];
        float mu = ts * (1.f / 192.f);
        float rstd = rsqrtf(tq * (1.f / 192.f) - mu * mu + 1e-5f);
#pragma unroll
        for (int j = 0; j < 3; j++) {
          const int gcol = wx * 48 + j * 16 + l15;
          float v = acc[i][j][r];
          ((u16*)outp)[grow * 192 + gcol] = f2bf(v);
          xmout[grow * 192 + gcol] = f2bf((v - mu) * rstd * g2c[j] + b2c[j]);
        }
      }
    }
    return;
  }

  const float qs = (EPI == 0 && nb == 0) ? kScale : 1.f;   // fold q scaling into qkv epilogue
#pragma unroll
  for (int i = 0; i < 4; i++) {
#pragma unroll
    for (int r = 0; r < 4; r++) {
      const int grow = mb * BM + wy * 64 + i * 16 + quad * 4 + r;
      long tokoff = 0;
      if constexpr (EPI == 3) tokoff = row2tok(grow) * 192;
#pragma unroll
      for (int j = 0; j < 3; j++) {
        const int gcol = nb * BN + wx * 48 + j * 16 + l15;
        float v = acc[i][j][r] + bcol[j];
        if constexpr (EPI == 0) {
          ((u16*)outp)[(long)grow * ND + gcol] = f2bf(v * qs);
        } else if constexpr (EPI == 2) {
          float gel = 0.5f * v * (1.0f + erff(v * 0.70710678118654752f));
          ((u16*)outp)[(long)grow * ND + gcol] = f2bf(gel);
        } else {
          ((float*)outp)[tokoff + gcol] = v + bf2f(x1[(long)grow * 192 + gcol]);
        }
      }
    }
  }
}

// ---- windowed MFMA attention: one block per (window, head) ----
// Q pre-scaled at qkv epilogue.  p = exp(s)*EB (no max-sub: |s| << 80), pre-normalized before PV.
__global__ __launch_bounds__(256, 3)
void attn_kernel(const u16* __restrict__ qkv, const float* __restrict__ EB, u16* __restrict__ attno) {
  __shared__ u16 uQK[17408];     // Qs[128*40] | Ks[128*40], later reused as Ps[128*136]
  __shared__ u16 Vt[32 * 136];   // V transposed [d][m]

  const int bid = blockIdx.x;
  const int wi = bid / kNH;           // global window 0..1023
  const int hh = bid - wi * kNH;      // head
  const int widx = wi & 511;          // window within image
  const int t = threadIdx.x;
  const int lane = t & 63, wv = t >> 6;
  const int quad = lane >> 4, l15 = lane & 15;

  {  // stage Q, K, V^T
    const int rr = t >> 1, half = (t & 1) * 16;
    const long base = (long)(wi * 128 + rr) * 576 + hh * 32 + half;
    uint4 q0 = *(const uint4*)(qkv + base);
    uint4 q1 = *(const uint4*)(qkv + base + 8);
    uint4 k0 = *(const uint4*)(qkv + base + 192);
    uint4 k1 = *(const uint4*)(qkv + base + 200);
    union { uint4 q[2]; u16 s[16]; } vv;
    vv.q[0] = *(const uint4*)(qkv + base + 384);
    vv.q[1] = *(const uint4*)(qkv + base + 392);
    u16* Qs = uQK;
    u16* Ks = uQK + 5120;
    *(uint4*)&Qs[rr * 40 + half] = q0;
    *(uint4*)&Qs[rr * 40 + half + 8] = q1;
    *(uint4*)&Ks[rr * 40 + half] = k0;
    *(uint4*)&Ks[rr * 40 + half + 8] = k1;
#pragma unroll
    for (int c = 0; c < 16; c++) Vt[(half + c) * 136 + rr] = vv.s[c];
  }
  __syncthreads();

  // S = Q K^T : each wave does rows [wv*32, wv*32+32) x 128 cols
  f32x4 sacc[2][8];
#pragma unroll
  for (int i = 0; i < 2; i++)
#pragma unroll
    for (int j = 0; j < 8; j++) sacc[i][j] = (f32x4){0.f, 0.f, 0.f, 0.f};
  {
    const u16* Qs = uQK;
    const u16* Ks = uQK + 5120;
    bf16x8 aq[2];
#pragma unroll
    for (int i = 0; i < 2; i++) aq[i] = *(const bf16x8*)&Qs[(wv * 32 + i * 16 + l15) * 40 + quad * 8];
    __builtin_amdgcn_s_setprio(1);
#pragma unroll
    for (int j = 0; j < 8; j++) {
      bf16x8 bk = *(const bf16x8*)&Ks[(j * 16 + l15) * 40 + quad * 8];
      sacc[0][j] = MFMA16(aq[0], bk, sacc[0][j]);
      sacc[1][j] = MFMA16(aq[1], bk, sacc[1][j]);
    }
    __builtin_amdgcn_s_setprio(0);
  }
  __syncthreads();  // all waves done with Qs/Ks; region becomes Ps

  // p = exp(s) * EB * maskbit, row-normalized, -> LDS bf16
  u16* Ps = uQK;  // [128][136]
  int ccnt[8];
#pragma unroll
  for (int j = 0; j < 8; j++) ccnt[j] = rcode(widx, j * 16 + l15);
  const float* EBh = EB + (hh << 14) + l15;
#pragma unroll
  for (int i = 0; i < 2; i++) {
#pragma unroll
    for (int r = 0; r < 4; r++) {
      int n = wv * 32 + i * 16 + quad * 4 + r;
      int rc = rcode(widx, n);
      const float* ebr = EBh + (n << 7);
      float pv[8];
      float l = 0.f;
#pragma unroll
      for (int j = 0; j < 8; j++) {
        float eb = ebr[j * 16];
        eb = (rc == ccnt[j]) ? eb : 0.f;
        float p = __expf(sacc[i][j][r]) * eb;
        pv[j] = p;
        l += p;
      }
      l += __shfl_xor(l, 1);
      l += __shfl_xor(l, 2);
      l += __shfl_xor(l, 4);
      l += __shfl_xor(l, 8);
      float rl = 1.f / l;
#pragma unroll
      for (int j = 0; j < 8; j++) Ps[n * 136 + j * 16 + l15] = f2bf(pv[j] * rl);
    }
  }
  __syncthreads();

  // O = P V : rows [wv*32, +32) x 32 cols
  f32x4 oacc[2][2];
#pragma unroll
  for (int i = 0; i < 2; i++)
#pragma unroll
    for (int j = 0; j < 2; j++) oacc[i][j] = (f32x4){0.f, 0.f, 0.f, 0.f};
  __builtin_amdgcn_s_setprio(1);
#pragma unroll
  for (int mc = 0; mc < 4; mc++) {
    bf16x8 ap[2], bv[2];
#pragma unroll
    for (int i = 0; i < 2; i++) ap[i] = *(const bf16x8*)&Ps[(wv * 32 + i * 16 + l15) * 136 + mc * 32 + quad * 8];
#pragma unroll
    for (int jj = 0; jj < 2; jj++) bv[jj] = *(const bf16x8*)&Vt[(jj * 16 + l15) * 136 + mc * 32 + quad * 8];
#pragma unroll
    for (int i = 0; i < 2; i++)
#pragma unroll
      for (int jj = 0; jj < 2; jj++) oacc[i][jj] = MFMA16(ap[i], bv[jj], oacc[i][jj]);
  }
  __builtin_amdgcn_s_setprio(0);
#pragma unroll
  for (int i = 0; i < 2; i++) {
#pragma unroll
    for (int jj = 0; jj < 2; jj++) {
#pragma unroll
      for (int r = 0; r < 4; r++) {
        int n = wv * 32 + i * 16 + quad * 4 + r;
        int d = jj * 16 + l15;
        attno[(long)(wi * 128 + n) * 192 + hh * 32 + d] = f2bf(oacc[i][jj][r]);
      }
    }
  }
}

extern "C" void kernel_launch(void* const* d_in, const int* in_sizes, int n_in,
                              void* d_out, int out_size, void* d_ws, size_t ws_size,
                              hipStream_t stream) {
  const float* x      = (const float*)d_in[0];
  const float* n1g    = (const float*)d_in[1];
  const float* n1b    = (const float*)d_in[2];
  const float* qkv_w  = (const float*)d_in[3];
  const float* qkv_b  = (const float*)d_in[4];
  const float* rpb    = (const float*)d_in[5];
  const float* proj_w = (const float*)d_in[6];
  const float* proj_b = (const float*)d_in[7];
  const float* n2g    = (const float*)d_in[8];
  const float* n2b    = (const float*)d_in[9];
  const float* fc1_w  = (const float*)d_in[10];
  const float* fc1_b  = (const float*)d_in[11];
  const float* fc2_w  = (const float*)d_in[12];
  const float* fc2_b  = (const float*)d_in[13];

  char* ws = (char*)d_ws;
  size_t off = 0;
  auto alloc = [&](size_t bytes) -> void* {
    void* p = ws + off;
    off += (bytes + 255) & ~(size_t)255;
    return p;
  };
  // lifetimes: xw: LN1out -> qkv; reused as attno (attn -> proj), reused as xm (LN2 -> fc1)
  //            qkvb: qkv (576 cols) -> attn; reused as fc1out (768 cols) -> fc2
  //            x1: residual stream bf16 in WINDOW order (proj out) -> fc2 epilogue.
  u16* WtQKV  = (u16*)alloc((size_t)110592 * 2);
  u16* WtPROJ = (u16*)alloc((size_t)36864 * 2);
  u16* WtFC1  = (u16*)alloc((size_t)147456 * 2);
  u16* WtFC2  = (u16*)alloc((size_t)147456 * 2);
  float* EB   = (float*)alloc((size_t)98304 * 4);   // exp(rel-pos-bias) [6][128][128]
  u16* xw     = (u16*)alloc((size_t)kTok * 192 * 2);
  u16* qkvb   = (u16*)alloc((size_t)kTok * 768 * 2);
  u16* x1     = (u16*)alloc((size_t)kTok * 192 * 2);
  u16* attno  = xw;
  u16* xm     = xw;

  transpose_kernel<<<(110592 + 255) / 256, 256, 0, stream>>>(qkv_w, WtQKV, 192, 576);
  transpose_kernel<<<(36864 + 255) / 256, 256, 0, stream>>>(proj_w, WtPROJ, 192, 192);
  transpose_kernel<<<(147456 + 255) / 256, 256, 0, stream>>>(fc1_w, WtFC1, 192, 768);
  transpose_kernel<<<(147456 + 255) / 256, 256, 0, stream>>>(fc2_w, WtFC2, 768, 192);
  ebias_kernel<<<98304 / 256, 256, 0, stream>>>(rpb, EB);

  ln1_kernel<<<kTok / 4, 256, 0, stream>>>(x, n1g, n1b, xw);
  // QKV: N=576 = 3 x 192 exact; q columns (nb==0) pre-scaled
  gemm_kernel<192, 576, 0><<<dim3(3, kTok / 128), 512, 0, stream>>>(xw, WtQKV, qkv_b, qkvb, nullptr, nullptr, nullptr, nullptr, nullptr);
  attn_kernel<<<1024 * kNH, 256, 0, stream>>>(qkvb, EB, attno);
  // proj: N=192, nb=1; gather resid (token order), write x1 + fused-LN2 xm (window order)
  gemm_kernel<192, 192, 1><<<dim3(1, kTok / 128), 512, 0, stream>>>(attno, WtPROJ, proj_b, x1, x, nullptr, n2g, n2b, xm);
  // fc1: N=768 = 4 x 192 exact
  gemm_kernel<192, 768, 2><<<dim3(4, kTok / 128), 512, 0, stream>>>(xm, WtFC1, fc1_b, qkvb, nullptr, nullptr, nullptr, nullptr, nullptr);
  // fc2: N=192, nb=1; scatter final fp32 out to token order
  gemm_kernel<768, 192, 3><<<dim3(1, kTok / 128), 512, 0, stream>>>(qkvb, WtFC2, fc2_b, d_out, nullptr, x1, nullptr, nullptr, nullptr);
}

// Round 8
// 568.916 us; speedup vs baseline: 1.2140x; 1.0206x over previous
//
#include <hip/hip_runtime.h>
#include <stdint.h>

typedef unsigned short u16;
typedef __bf16 bf16x8 __attribute__((ext_vector_type(8)));
typedef float f32x4 __attribute__((ext_vector_type(4)));

#define MFMA16(a, b, c) __builtin_amdgcn_mfma_f32_16x16x32_bf16(a, b, c, 0, 0, 0)

// ---- problem constants ----
static constexpr int kC = 192;
static constexpr int kNH = 6;
static constexpr int kTok = 131072;          // B * T*H*W
static constexpr float kScale = 0.17677669529663687f;  // 32^-0.5

__device__ __forceinline__ float bf2f(u16 u) {
  union { uint32_t i; float f; } c; c.i = (uint32_t)u << 16; return c.f;
}
__device__ __forceinline__ u16 f2bf(float f) {
  union { float f; uint32_t i; } c; c.f = f;
  uint32_t r = c.i + 0x7fffu + ((c.i >> 16) & 1u);
  return (u16)(r >> 16);
}

// async global->LDS, 16B per lane; lds dest must be wave-uniform base (+lane*16 by HW)
__device__ __forceinline__ void gload_lds16(const void* g, void* l) {
  __builtin_amdgcn_global_load_lds((const __attribute__((address_space(1))) void*)g,
                                   (__attribute__((address_space(3))) void*)l, 16, 0, 0);
}

// shift-mask region code for (window-in-image, token-in-window), shifted coords
__device__ __forceinline__ int rcode(int widx, int n) {
  int t = ((widx >> 6) << 3) + (n >> 4);
  int h = (((widx >> 3) & 7) << 2) + ((n >> 2) & 3);
  int w = ((widx & 7) << 2) + (n & 3);
  int rt = (t < 56) ? 0 : ((t < 60) ? 1 : 2);
  int rh = (h < 28) ? 0 : ((h < 30) ? 1 : 2);
  int rw = (w < 28) ? 0 : ((w < 30) ? 1 : 2);
  return rt * 9 + rh * 3 + rw;
}

// window-row -> token index (window reverse + un-shift)
__device__ __forceinline__ long row2tok(int grow) {
  int bb = grow >> 16, widx = (grow >> 7) & 511, n = grow & 127;
  int tp = ((widx >> 6) << 3) + (n >> 4);
  int hp = (((widx >> 3) & 7) << 2) + ((n >> 2) & 3);
  int wp = ((widx & 7) << 2) + (n & 3);
  int tt = (tp + 4) & 63, hh2 = (hp + 2) & 31, ww2 = (wp + 2) & 31;
  return ((long)bb << 16) + (tt << 10) + (hh2 << 5) + ww2;
}

// ---- weight transpose + bf16 convert: Wt[n][k] = bf16(W[k][n])  (W fp32) ----
__global__ void transpose_kernel(const float* __restrict__ W, u16* __restrict__ Wt, int K, int Nd) {
  int idx = blockIdx.x * 256 + threadIdx.x;
  if (idx < K * Nd) {
    int n = idx / K;
    int k = idx - n * K;
    Wt[idx] = f2bf(W[(long)k * Nd + n]);
  }
}

// ---- exp(rel-pos-bias) table: EB[hh][n][m] = exp(rpb_table[relidx(n,m)][hh]) ----
// softmax(s + b) == (exp(s)*exp(b)) / sum(exp(s)*exp(b))  (shift-invariant; |s| << 80 here)
__global__ void ebias_kernel(const float* __restrict__ rpb, float* __restrict__ EB) {
  int idx = blockIdx.x * 256 + threadIdx.x;   // < 6*128*128 = 98304
  int hh = idx >> 14;
  int rem = idx & 16383;
  int n = rem >> 7, m = rem & 127;
  int tn = n >> 4, hn = (n >> 2) & 3, wn = n & 3;
  int tm = m >> 4, hm = (m >> 2) & 3, wm = m & 3;
  // faithful to reference: (dt+7)*15 + (dh+3)*7 + (dw+3)
  int ridx = (tn - tm + 7) * 15 + (hn - hm + 3) * 7 + (wn - wm + 3);
  EB[idx] = __expf(rpb[ridx * 6 + hh]);
}

// ---- LN1 + cyclic shift + window partition (fp32 in, bf16 out, permuted rows) ----
__global__ __launch_bounds__(256) void ln1_kernel(const float* __restrict__ x, const float* __restrict__ g,
                                                  const float* __restrict__ b, u16* __restrict__ xw) {
  int wv = threadIdx.x >> 6, lane = threadIdx.x & 63;
  int tok = blockIdx.x * 4 + wv;
  const float* xr = x + (long)tok * kC;
  float v0 = xr[lane], v1 = xr[lane + 64], v2 = xr[lane + 128];
  float s = v0 + v1 + v2;
  for (int m = 32; m; m >>= 1) s += __shfl_xor(s, m);
  float mu = s * (1.f / 192.f);
  float d0 = v0 - mu, d1 = v1 - mu, d2 = v2 - mu;
  float q = d0 * d0 + d1 * d1 + d2 * d2;
  for (int m = 32; m; m >>= 1) q += __shfl_xor(q, m);
  float rstd = rsqrtf(q * (1.f / 192.f) + 1e-5f);
  int bb = tok >> 16, loc = tok & 65535;
  int t = loc >> 10, h = (loc >> 5) & 31, w = loc & 31;
  int tp = (t + 60) & 63, hp = (h + 30) & 31, wp = (w + 30) & 31;
  int widx = ((tp >> 3) << 6) + ((hp >> 2) << 3) + (wp >> 2);
  int n = ((tp & 7) << 4) + ((hp & 3) << 2) + (wp & 3);
  long row = (((long)bb * 512 + widx) << 7) + n;
  u16* o = xw + row * kC;
  o[lane]       = f2bf(d0 * rstd * g[lane]       + b[lane]);
  o[lane + 64]  = f2bf(d1 * rstd * g[lane + 64]  + b[lane + 64]);
  o[lane + 128] = f2bf(d2 * rstd * g[lane + 128] + b[lane + 128]);
}

// ---- MFMA GEMM: 128x192 tile, 8 waves (2M x 4N, each 64x48) ----
// 3-buffer pipeline: 1 barrier/K-step, counted vmcnt (never 0 except final drain iteration).
// FINAL iteration MUST use vmcnt(0): no stage(tt+1) was issued, so the counted wait would
// be satisfied without stage(tt)'s own loads having landed (R7 correctness bug).
// LDS XOR-swizzle: physical chunk = logical ^ ((row>>1)&3); applied on the GLOBAL source
// (gload_lds dest stays linear) and on the ds_read offsets (both-sides-or-neither).
// out[M][ND] = A[M][K] @ Wt[ND][K]^T + bias(fp32), with epilogues.  ND % 192 == 0; M % 128 == 0.
// EPI 0: store bf16; nb==0 (q columns) scaled by kScale              (qkv)
// EPI 1 (requires grid nb==1): + gather resid(fp32, token order), store bf16 x1 (window order)
//        AND fused LN2 -> store bf16 xm (window order)               (proj)
// EPI 2: erf-GELU, store bf16                                        (fc1)
// EPI 3: + x1w(bf16, window order), SCATTER-store fp32 token order   (fc2 -> d_out)
template <int K, int ND, int EPI>
__global__ __launch_bounds__(512, 4)
void gemm_kernel(const u16* __restrict__ A, const u16* __restrict__ Wt,
                 const float* __restrict__ bias, void* __restrict__ outp,
                 const float* __restrict__ resid, const u16* __restrict__ x1,
                 const float* __restrict__ g2, const float* __restrict__ b2,
                 u16* __restrict__ xmout) {
  static_assert(K % 32 == 0 && ND % 192 == 0, "tiling");
  constexpr int BM = 128, BN = 192;
  constexpr int ROWS = BM + BN;        // 320 rows of 32 bf16 (64 B) each
  constexpr int RG = ROWS / 16;        // 20 row-groups (1 KB each)
  constexpr int NT = K / 32;
  static_assert(NT >= 2, "pipeline depth");

  __shared__ u16 lds[3][ROWS * 32];    // 3 x 20 KB

  const int t = threadIdx.x;
  const int nb = blockIdx.x, mb = blockIdx.y;
  const int lane = t & 63, wv = t >> 6;
  const int wy = wv >> 2, wx = wv & 3;      // wave grid 2 (M) x 4 (N); per-wave 64x48
  const int quad = lane >> 4, l15 = lane & 15;

  f32x4 acc[4][3];
#pragma unroll
  for (int i = 0; i < 4; i++)
#pragma unroll
    for (int j = 0; j < 3; j++) acc[i][j] = (f32x4){0.f, 0.f, 0.f, 0.f};

  // staging: wave wv stages row-groups rr = wv, wv+8, wv+16 (rr < 20); wv<4 -> 3, wv>=4 -> 2 loads
  // lane l covers LDS phys (row = rr*16 + l/4, chunk p = l&3); source chunk = p ^ ((row>>1)&3)
  const u16* sp[3];
#pragma unroll
  for (int ii = 0; ii < 3; ii++) {
    int rr = wv + ii * 8;
    if (rr < RG) {
      int row = rr * 16 + (lane >> 2);
      int c = (((lane & 3) ^ ((row >> 1) & 3)) * 8);
      sp[ii] = (row < BM) ? A + (long)(mb * BM + row) * K + c
                          : Wt + (long)(nb * BN + (row - BM)) * K + c;
    } else {
      sp[ii] = nullptr;
    }
  }

  auto stage = [&](int buf, int k0) {
    u16* lb = &lds[buf][0];
#pragma unroll
    for (int ii = 0; ii < 3; ii++) {
      int rr = wv + ii * 8;
      if (rr < RG) gload_lds16(sp[ii] + k0, lb + rr * 512);
    }
  };

  // loop-invariant swizzled read offsets (u16 units)
  int aoff[4], boff[3];
#pragma unroll
  for (int i = 0; i < 4; i++) {
    int row = wy * 64 + i * 16 + l15;
    aoff[i] = row * 32 + ((quad ^ ((row >> 1) & 3)) << 3);
  }
#pragma unroll
  for (int j = 0; j < 3; j++) {
    int row = BM + wx * 48 + j * 16 + l15;
    boff[j] = row * 32 + ((quad ^ ((row >> 1) & 3)) << 3);
  }

  stage(0, 0);
  stage(1, 32);

  int cur = 0, nx2 = 2;                // buffer of tile tt, and of tile tt+2
#pragma unroll
  for (int tt = 0; tt < NT; ++tt) {
    // wait: my stage-tt loads landed.  Steady state: the <=n_w outstanding are stage(tt+1)'s
    // (FIFO).  Final iteration: no stage(tt+1) exists -> must drain fully.
    if (tt == NT - 1) asm volatile("s_waitcnt vmcnt(0)" ::: "memory");
    else if (wv < 4)  asm volatile("s_waitcnt vmcnt(3)" ::: "memory");
    else              asm volatile("s_waitcnt vmcnt(2)" ::: "memory");
    __builtin_amdgcn_s_barrier();      // all waves' stage-tt visible; all done reading buf nx2
    __builtin_amdgcn_sched_barrier(0);
    if (tt + 2 < NT) stage(nx2, (tt + 2) * 32);
    const u16* lb = &lds[cur][0];
    bf16x8 af[4], bfr[3];
#pragma unroll
    for (int i = 0; i < 4; i++) af[i] = *(const bf16x8*)&lb[aoff[i]];
#pragma unroll
    for (int j = 0; j < 3; j++) bfr[j] = *(const bf16x8*)&lb[boff[j]];
#pragma unroll
    for (int i = 0; i < 4; i++)
#pragma unroll
      for (int j = 0; j < 3; j++) acc[i][j] = MFMA16(af[i], bfr[j], acc[i][j]);
    cur = (cur == 2) ? 0 : cur + 1;
    nx2 = (nx2 == 2) ? 0 : nx2 + 1;
  }

  // ---- epilogue ----
  float bcol[3];
#pragma unroll
  for (int j = 0; j < 3; j++) bcol[j] = bias[nb * BN + wx * 48 + j * 16 + l15];

  if constexpr (EPI == 1) {
    // proj + residual + fused LN2.  Requires gridDim.x == 1 (full 192-wide rows per block).
    __syncthreads();                        // all waves done with LDS compute buffers
    float* partS = (float*)&lds[0][0];      // [128][4]
    float* partQ = partS + 512;             // [128][4]
    float g2c[3], b2c[3];
#pragma unroll
    for (int j = 0; j < 3; j++) {
      g2c[j] = g2[wx * 48 + j * 16 + l15];
      b2c[j] = b2[wx * 48 + j * 16 + l15];
    }
#pragma unroll
    for (int i = 0; i < 4; i++) {
#pragma unroll
      for (int r = 0; r < 4; r++) {
        const int lrow = wy * 64 + i * 16 + quad * 4 + r;
        const long tokoff = row2tok(mb * BM + lrow) * 192;
        float s1 = 0.f, s2 = 0.f;
#pragma unroll
        for (int j = 0; j < 3; j++) {
          const int gcol = wx * 48 + j * 16 + l15;
          float v = acc[i][j][r] + bcol[j] + resid[tokoff + gcol];
          acc[i][j][r] = v;
          s1 += v; s2 += v * v;
        }
        s1 += __shfl_xor(s1, 1); s1 += __shfl_xor(s1, 2); s1 += __shfl_xor(s1, 4); s1 += __shfl_xor(s1, 8);
        s2 += __shfl_xor(s2, 1); s2 += __shfl_xor(s2, 2); s2 += __shfl_xor(s2, 4); s2 += __shfl_xor(s2, 8);
        if (l15 == 0) { partS[lrow * 4 + wx] = s1; partQ[lrow * 4 + wx] = s2; }
      }
    }
    __syncthreads();
#pragma unroll
    for (int i = 0; i < 4; i++) {
#pragma unroll
      for (int r = 0; r < 4; r++) {
        const int lrow = wy * 64 + i * 16 + quad * 4 + r;
        const long grow = mb * BM + lrow;
        float ts = partS[lrow * 4 + 0] + partS[lrow * 4 + 1] + partS[lrow * 4 + 2] + partS[lrow * 4 + 3];
        float tq = partQ[lrow * 4 + 0] + partQ[lrow * 4 + 1] + partQ[lrow * 4 + 2] + partQ[lrow * 4 + 3];
        float mu = ts * (1.f / 192.f);
        float rstd = rsqrtf(tq * (1.f / 192.f) - mu * mu + 1e-5f);
#pragma unroll
        for (int j = 0; j < 3; j++) {
          const int gcol = wx * 48 + j * 16 + l15;
          float v = acc[i][j][r];
          ((u16*)outp)[grow * 192 + gcol] = f2bf(v);
          xmout[grow * 192 + gcol] = f2bf((v - mu) * rstd * g2c[j] + b2c[j]);
        }
      }
    }
    return;
  }

  const float qs = (EPI == 0 && nb == 0) ? kScale : 1.f;   // fold q scaling into qkv epilogue
#pragma unroll
  for (int i = 0; i < 4; i++) {
#pragma unroll
    for (int r = 0; r < 4; r++) {
      const int grow = mb * BM + wy * 64 + i * 16 + quad * 4 + r;
      long tokoff = 0;
      if constexpr (EPI == 3) tokoff = row2tok(grow) * 192;
#pragma unroll
      for (int j = 0; j < 3; j++) {
        const int gcol = nb * BN + wx * 48 + j * 16 + l15;
        float v = acc[i][j][r] + bcol[j];
        if constexpr (EPI == 0) {
          ((u16*)outp)[(long)grow * ND + gcol] = f2bf(v * qs);
        } else if constexpr (EPI == 2) {
          float gel = 0.5f * v * (1.0f + erff(v * 0.70710678118654752f));
          ((u16*)outp)[(long)grow * ND + gcol] = f2bf(gel);
        } else {
          ((float*)outp)[tokoff + gcol] = v + bf2f(x1[(long)grow * 192 + gcol]);
        }
      }
    }
  }
}

// ---- windowed MFMA attention: one block per (window, head) ----
// Q pre-scaled at qkv epilogue.  p = exp(s)*EB (no max-sub: |s| << 80), pre-normalized before PV.
__global__ __launch_bounds__(256, 3)
void attn_kernel(const u16* __restrict__ qkv, const float* __restrict__ EB, u16* __restrict__ attno) {
  __shared__ u16 uQK[17408];     // Qs[128*40] | Ks[128*40], later reused as Ps[128*136]
  __shared__ u16 Vt[32 * 136];   // V transposed [d][m]

  const int bid = blockIdx.x;
  const int wi = bid / kNH;           // global window 0..1023
  const int hh = bid - wi * kNH;      // head
  const int widx = wi & 511;          // window within image
  const int t = threadIdx.x;
  const int lane = t & 63, wv = t >> 6;
  const int quad = lane >> 4, l15 = lane & 15;

  {  // stage Q, K, V^T
    const int rr = t >> 1, half = (t & 1) * 16;
    const long base = (long)(wi * 128 + rr) * 576 + hh * 32 + half;
    uint4 q0 = *(const uint4*)(qkv + base);
    uint4 q1 = *(const uint4*)(qkv + base + 8);
    uint4 k0 = *(const uint4*)(qkv + base + 192);
    uint4 k1 = *(const uint4*)(qkv + base + 200);
    union { uint4 q[2]; u16 s[16]; } vv;
    vv.q[0] = *(const uint4*)(qkv + base + 384);
    vv.q[1] = *(const uint4*)(qkv + base + 392);
    u16* Qs = uQK;
    u16* Ks = uQK + 5120;
    *(uint4*)&Qs[rr * 40 + half] = q0;
    *(uint4*)&Qs[rr * 40 + half + 8] = q1;
    *(uint4*)&Ks[rr * 40 + half] = k0;
    *(uint4*)&Ks[rr * 40 + half + 8] = k1;
#pragma unroll
    for (int c = 0; c < 16; c++) Vt[(half + c) * 136 + rr] = vv.s[c];
  }
  __syncthreads();

  // S = Q K^T : each wave does rows [wv*32, wv*32+32) x 128 cols
  f32x4 sacc[2][8];
#pragma unroll
  for (int i = 0; i < 2; i++)
#pragma unroll
    for (int j = 0; j < 8; j++) sacc[i][j] = (f32x4){0.f, 0.f, 0.f, 0.f};
  {
    const u16* Qs = uQK;
    const u16* Ks = uQK + 5120;
    bf16x8 aq[2];
#pragma unroll
    for (int i = 0; i < 2; i++) aq[i] = *(const bf16x8*)&Qs[(wv * 32 + i * 16 + l15) * 40 + quad * 8];
    __builtin_amdgcn_s_setprio(1);
#pragma unroll
    for (int j = 0; j < 8; j++) {
      bf16x8 bk = *(const bf16x8*)&Ks[(j * 16 + l15) * 40 + quad * 8];
      sacc[0][j] = MFMA16(aq[0], bk, sacc[0][j]);
      sacc[1][j] = MFMA16(aq[1], bk, sacc[1][j]);
    }
    __builtin_amdgcn_s_setprio(0);
  }
  __syncthreads();  // all waves done with Qs/Ks; region becomes Ps

  // p = exp(s) * EB * maskbit, row-normalized, -> LDS bf16
  u16* Ps = uQK;  // [128][136]
  int ccnt[8];
#pragma unroll
  for (int j = 0; j < 8; j++) ccnt[j] = rcode(widx, j * 16 + l15);
  const float* EBh = EB + (hh << 14) + l15;
#pragma unroll
  for (int i = 0; i < 2; i++) {
#pragma unroll
    for (int r = 0; r < 4; r++) {
      int n = wv * 32 + i * 16 + quad * 4 + r;
      int rc = rcode(widx, n);
      const float* ebr = EBh + (n << 7);
      float pv[8];
      float l = 0.f;
#pragma unroll
      for (int j = 0; j < 8; j++) {
        float eb = ebr[j * 16];
        eb = (rc == ccnt[j]) ? eb : 0.f;
        float p = __expf(sacc[i][j][r]) * eb;
        pv[j] = p;
        l += p;
      }
      l += __shfl_xor(l, 1);
      l += __shfl_xor(l, 2);
      l += __shfl_xor(l, 4);
      l += __shfl_xor(l, 8);
      float rl = 1.f / l;
#pragma unroll
      for (int j = 0; j < 8; j++) Ps[n * 136 + j * 16 + l15] = f2bf(pv[j] * rl);
    }
  }
  __syncthreads();

  // O = P V : rows [wv*32, +32) x 32 cols
  f32x4 oacc[2][2];
#pragma unroll
  for (int i = 0; i < 2; i++)
#pragma unroll
    for (int j = 0; j < 2; j++) oacc[i][j] = (f32x4){0.f, 0.f, 0.f, 0.f};
  __builtin_amdgcn_s_setprio(1);
#pragma unroll
  for (int mc = 0; mc < 4; mc++) {
    bf16x8 ap[2], bv[2];
#pragma unroll
    for (int i = 0; i < 2; i++) ap[i] = *(const bf16x8*)&Ps[(wv * 32 + i * 16 + l15) * 136 + mc * 32 + quad * 8];
#pragma unroll
    for (int jj = 0; jj < 2; jj++) bv[jj] = *(const bf16x8*)&Vt[(jj * 16 + l15) * 136 + mc * 32 + quad * 8];
#pragma unroll
    for (int i = 0; i < 2; i++)
#pragma unroll
      for (int jj = 0; jj < 2; jj++) oacc[i][jj] = MFMA16(ap[i], bv[jj], oacc[i][jj]);
  }
  __builtin_amdgcn_s_setprio(0);
#pragma unroll
  for (int i = 0; i < 2; i++) {
#pragma unroll
    for (int jj = 0; jj < 2; jj++) {
#pragma unroll
      for (int r = 0; r < 4; r++) {
        int n = wv * 32 + i * 16 + quad * 4 + r;
        int d = jj * 16 + l15;
        attno[(long)(wi * 128 + n) * 192 + hh * 32 + d] = f2bf(oacc[i][jj][r]);
      }
    }
  }
}

extern "C" void kernel_launch(void* const* d_in, const int* in_sizes, int n_in,
                              void* d_out, int out_size, void* d_ws, size_t ws_size,
                              hipStream_t stream) {
  const float* x      = (const float*)d_in[0];
  const float* n1g    = (const float*)d_in[1];
  const float* n1b    = (const float*)d_in[2];
  const float* qkv_w  = (const float*)d_in[3];
  const float* qkv_b  = (const float*)d_in[4];
  const float* rpb    = (const float*)d_in[5];
  const float* proj_w = (const float*)d_in[6];
  const float* proj_b = (const float*)d_in[7];
  const float* n2g    = (const float*)d_in[8];
  const float* n2b    = (const float*)d_in[9];
  const float* fc1_w  = (const float*)d_in[10];
  const float* fc1_b  = (const float*)d_in[11];
  const float* fc2_w  = (const float*)d_in[12];
  const float* fc2_b  = (const float*)d_in[13];

  char* ws = (char*)d_ws;
  size_t off = 0;
  auto alloc = [&](size_t bytes) -> void* {
    void* p = ws + off;
    off += (bytes + 255) & ~(size_t)255;
    return p;
  };
  // lifetimes: xw: LN1out -> qkv; reused as attno (attn -> proj), reused as xm (LN2 -> fc1)
  //            qkvb: qkv (576 cols) -> attn; reused as fc1out (768 cols) -> fc2
  //            x1: residual stream bf16 in WINDOW order (proj out) -> fc2 epilogue.
  u16* WtQKV  = (u16*)alloc((size_t)110592 * 2);
  u16* WtPROJ = (u16*)alloc((size_t)36864 * 2);
  u16* WtFC1  = (u16*)alloc((size_t)147456 * 2);
  u16* WtFC2  = (u16*)alloc((size_t)147456 * 2);
  float* EB   = (float*)alloc((size_t)98304 * 4);   // exp(rel-pos-bias) [6][128][128]
  u16* xw     = (u16*)alloc((size_t)kTok * 192 * 2);
  u16* qkvb   = (u16*)alloc((size_t)kTok * 768 * 2);
  u16* x1     = (u16*)alloc((size_t)kTok * 192 * 2);
  u16* attno  = xw;
  u16* xm     = xw;

  transpose_kernel<<<(110592 + 255) / 256, 256, 0, stream>>>(qkv_w, WtQKV, 192, 576);
  transpose_kernel<<<(36864 + 255) / 256, 256, 0, stream>>>(proj_w, WtPROJ, 192, 192);
  transpose_kernel<<<(147456 + 255) / 256, 256, 0, stream>>>(fc1_w, WtFC1, 192, 768);
  transpose_kernel<<<(147456 + 255) / 256, 256, 0, stream>>>(fc2_w, WtFC2, 768, 192);
  ebias_kernel<<<98304 / 256, 256, 0, stream>>>(rpb, EB);

  ln1_kernel<<<kTok / 4, 256, 0, stream>>>(x, n1g, n1b, xw);
  // QKV: N=576 = 3 x 192 exact; q columns (nb==0) pre-scaled
  gemm_kernel<192, 576, 0><<<dim3(3, kTok / 128), 512, 0, stream>>>(xw, WtQKV, qkv_b, qkvb, nullptr, nullptr, nullptr, nullptr, nullptr);
  attn_kernel<<<1024 * kNH, 256, 0, stream>>>(qkvb, EB, attno);
  // proj: N=192, nb=1; gather resid (token order), write x1 + fused-LN2 xm (window order)
  gemm_kernel<192, 192, 1><<<dim3(1, kTok / 128), 512, 0, stream>>>(attno, WtPROJ, proj_b, x1, x, nullptr, n2g, n2b, xm);
  // fc1: N=768 = 4 x 192 exact
  gemm_kernel<192, 768, 2><<<dim3(4, kTok / 128), 512, 0, stream>>>(xm, WtFC1, fc1_b, qkvb, nullptr, nullptr, nullptr, nullptr, nullptr);
  // fc2: N=192, nb=1; scatter final fp32 out to token order
  gemm_kernel<768, 192, 3><<<dim3(1, kTok / 128), 512, 0, stream>>>(qkvb, WtFC2, fc2_b, d_out, nullptr, x1, nullptr, nullptr, nullptr);
}

// Round 9
// 558.775 us; speedup vs baseline: 1.2360x; 1.0181x over previous
//
#include <hip/hip_runtime.h>
#include <stdint.h>

typedef unsigned short u16;
typedef __bf16 bf16x8 __attribute__((ext_vector_type(8)));
typedef float f32x4 __attribute__((ext_vector_type(4)));

#define MFMA16(a, b, c) __builtin_amdgcn_mfma_f32_16x16x32_bf16(a, b, c, 0, 0, 0)

// ---- problem constants ----
static constexpr int kC = 192;
static constexpr int kNH = 6;
static constexpr int kTok = 131072;          // B * T*H*W
static constexpr float kScale = 0.17677669529663687f;  // 32^-0.5

__device__ __forceinline__ float bf2f(u16 u) {
  union { uint32_t i; float f; } c; c.i = (uint32_t)u << 16; return c.f;
}
__device__ __forceinline__ u16 f2bf(float f) {
  union { float f; uint32_t i; } c; c.f = f;
  uint32_t r = c.i + 0x7fffu + ((c.i >> 16) & 1u);
  return (u16)(r >> 16);
}

// async global->LDS, 16B per lane; lds dest must be wave-uniform base (+lane*16 by HW)
__device__ __forceinline__ void gload_lds16(const void* g, void* l) {
  __builtin_amdgcn_global_load_lds((const __attribute__((address_space(1))) void*)g,
                                   (__attribute__((address_space(3))) void*)l, 16, 0, 0);
}

// tanh-approx GELU (max |delta| vs exact erf-GELU ~3e-4; amplified to ~6e-3 at output, well
// under threshold).  gelu(v) = v - v / (exp(2*c*(v + 0.044715 v^3)) + 1),  c = sqrt(2/pi)
__device__ __forceinline__ float gelu_tanh(float v) {
  float p = fmaf(v * v, 0.07135481627f, 1.59576912161f);   // 2c*0.044715, 2c
  float e = __expf(v * p);
  float r = __builtin_amdgcn_rcpf(e + 1.0f);
  return v - v * r;
}

// shift-mask region code for (window-in-image, token-in-window), shifted coords
__device__ __forceinline__ int rcode(int widx, int n) {
  int t = ((widx >> 6) << 3) + (n >> 4);
  int h = (((widx >> 3) & 7) << 2) + ((n >> 2) & 3);
  int w = ((widx & 7) << 2) + (n & 3);
  int rt = (t < 56) ? 0 : ((t < 60) ? 1 : 2);
  int rh = (h < 28) ? 0 : ((h < 30) ? 1 : 2);
  int rw = (w < 28) ? 0 : ((w < 30) ? 1 : 2);
  return rt * 9 + rh * 3 + rw;
}

// window-row -> token index (window reverse + un-shift)
__device__ __forceinline__ long row2tok(int grow) {
  int bb = grow >> 16, widx = (grow >> 7) & 511, n = grow & 127;
  int tp = ((widx >> 6) << 3) + (n >> 4);
  int hp = (((widx >> 3) & 7) << 2) + ((n >> 2) & 3);
  int wp = ((widx & 7) << 2) + (n & 3);
  int tt = (tp + 4) & 63, hh2 = (hp + 2) & 31, ww2 = (wp + 2) & 31;
  return ((long)bb << 16) + (tt << 10) + (hh2 << 5) + ww2;
}

// ---- weight transpose + bf16 convert: Wt[n][k] = bf16(W[k][n])  (W fp32) ----
__global__ void transpose_kernel(const float* __restrict__ W, u16* __restrict__ Wt, int K, int Nd) {
  int idx = blockIdx.x * 256 + threadIdx.x;
  if (idx < K * Nd) {
    int n = idx / K;
    int k = idx - n * K;
    Wt[idx] = f2bf(W[(long)k * Nd + n]);
  }
}

// ---- exp(rel-pos-bias) table: EB[hh][n][m] = exp(rpb_table[relidx(n,m)][hh]) ----
// softmax(s + b) == (exp(s)*exp(b)) / sum(exp(s)*exp(b))  (shift-invariant; |s| << 80 here)
__global__ void ebias_kernel(const float* __restrict__ rpb, float* __restrict__ EB) {
  int idx = blockIdx.x * 256 + threadIdx.x;   // < 6*128*128 = 98304
  int hh = idx >> 14;
  int rem = idx & 16383;
  int n = rem >> 7, m = rem & 127;
  int tn = n >> 4, hn = (n >> 2) & 3, wn = n & 3;
  int tm = m >> 4, hm = (m >> 2) & 3, wm = m & 3;
  // faithful to reference: (dt+7)*15 + (dh+3)*7 + (dw+3)
  int ridx = (tn - tm + 7) * 15 + (hn - hm + 3) * 7 + (wn - wm + 3);
  EB[idx] = __expf(rpb[ridx * 6 + hh]);
}

// ---- LN1 + cyclic shift + window partition (fp32 in, bf16 out, permuted rows) ----
__global__ __launch_bounds__(256) void ln1_kernel(const float* __restrict__ x, const float* __restrict__ g,
                                                  const float* __restrict__ b, u16* __restrict__ xw) {
  int wv = threadIdx.x >> 6, lane = threadIdx.x & 63;
  int tok = blockIdx.x * 4 + wv;
  const float* xr = x + (long)tok * kC;
  float v0 = xr[lane], v1 = xr[lane + 64], v2 = xr[lane + 128];
  float s = v0 + v1 + v2;
  for (int m = 32; m; m >>= 1) s += __shfl_xor(s, m);
  float mu = s * (1.f / 192.f);
  float d0 = v0 - mu, d1 = v1 - mu, d2 = v2 - mu;
  float q = d0 * d0 + d1 * d1 + d2 * d2;
  for (int m = 32; m; m >>= 1) q += __shfl_xor(q, m);
  float rstd = rsqrtf(q * (1.f / 192.f) + 1e-5f);
  int bb = tok >> 16, loc = tok & 65535;
  int t = loc >> 10, h = (loc >> 5) & 31, w = loc & 31;
  int tp = (t + 60) & 63, hp = (h + 30) & 31, wp = (w + 30) & 31;
  int widx = ((tp >> 3) << 6) + ((hp >> 2) << 3) + (wp >> 2);
  int n = ((tp & 7) << 4) + ((hp & 3) << 2) + (wp & 3);
  long row = (((long)bb * 512 + widx) << 7) + n;
  u16* o = xw + row * kC;
  o[lane]       = f2bf(d0 * rstd * g[lane]       + b[lane]);
  o[lane + 64]  = f2bf(d1 * rstd * g[lane + 64]  + b[lane + 64]);
  o[lane + 128] = f2bf(d2 * rstd * g[lane + 128] + b[lane + 128]);
}

// ---- MFMA GEMM: 128x192 tile, 4 waves (2M x 2N, each 64x96) ----
// Per-wave 64x96 (acc[4][6]): LDS frag traffic 10KB per 24 MFMA = 0.026 B/FLOP (vs 0.036 at
// 64x48) -> LDS read BW stops binding; GEMMs move to their HBM floors.
// 3-buffer pipeline: 1 barrier/K-step, counted vmcnt(5) (never 0 except final drain iter).
// LDS XOR-swizzle both-sides (source chunk pre-swizzled, reads swizzled); gload_lds dest linear.
// 2 blocks/CU (LDS 60KB/block, ~180 regs incl acc).
// EPI 0: store bf16; nb==0 (q columns) scaled by kScale              (qkv)
// EPI 1 (requires grid nb==1): + gather resid(fp32, token order), store bf16 x1 (window order)
//        AND fused LN2 -> store bf16 xm (window order)               (proj)
// EPI 2: tanh-GELU, store bf16                                       (fc1)
// EPI 3: + x1w(bf16, window order), SCATTER-store fp32 token order   (fc2 -> d_out)
template <int K, int ND, int EPI>
__global__ __launch_bounds__(256, 2)
void gemm_kernel(const u16* __restrict__ A, const u16* __restrict__ Wt,
                 const float* __restrict__ bias, void* __restrict__ outp,
                 const float* __restrict__ resid, const u16* __restrict__ x1,
                 const float* __restrict__ g2, const float* __restrict__ b2,
                 u16* __restrict__ xmout) {
  static_assert(K % 32 == 0 && ND % 192 == 0, "tiling");
  constexpr int BM = 128, BN = 192;
  constexpr int ROWS = BM + BN;        // 320 rows of 32 bf16 (64 B) each
  constexpr int NT = K / 32;
  static_assert(NT >= 2, "pipeline depth");

  __shared__ u16 lds[3][ROWS * 32];    // 3 x 20 KB

  const int t = threadIdx.x;
  const int nb = blockIdx.x, mb = blockIdx.y;
  const int lane = t & 63, wv = t >> 6;
  const int wy = wv >> 1, wx = wv & 1;      // wave grid 2 (M) x 2 (N); per-wave 64x96
  const int quad = lane >> 4, l15 = lane & 15;

  f32x4 acc[4][6];
#pragma unroll
  for (int i = 0; i < 4; i++)
#pragma unroll
    for (int j = 0; j < 6; j++) acc[i][j] = (f32x4){0.f, 0.f, 0.f, 0.f};

  // staging: wave wv stages row-groups rr = wv, wv+4, ..., wv+16 (RG=20 exact, 5 loads/wave)
  // lane l covers LDS phys (row = rr*16 + l/4, chunk p = l&3); source chunk = p ^ ((row>>1)&3)
  const u16* sp[5];
#pragma unroll
  for (int ii = 0; ii < 5; ii++) {
    int rr = wv + ii * 4;
    int row = rr * 16 + (lane >> 2);
    int c = (((lane & 3) ^ ((row >> 1) & 3)) * 8);
    sp[ii] = (row < BM) ? A + (long)(mb * BM + row) * K + c
                        : Wt + (long)(nb * BN + (row - BM)) * K + c;
  }

  auto stage = [&](int buf, int k0) {
    u16* lb = &lds[buf][0];
#pragma unroll
    for (int ii = 0; ii < 5; ii++) {
      int rr = wv + ii * 4;
      gload_lds16(sp[ii] + k0, lb + rr * 512);
    }
  };

  // loop-invariant swizzled read offsets (u16 units)
  int aoff[4], boff[6];
#pragma unroll
  for (int i = 0; i < 4; i++) {
    int row = wy * 64 + i * 16 + l15;
    aoff[i] = row * 32 + ((quad ^ ((row >> 1) & 3)) << 3);
  }
#pragma unroll
  for (int j = 0; j < 6; j++) {
    int row = BM + wx * 96 + j * 16 + l15;
    boff[j] = row * 32 + ((quad ^ ((row >> 1) & 3)) << 3);
  }

  stage(0, 0);
  stage(1, 32);

  int cur = 0, nx2 = 2;                // buffer of tile tt, and of tile tt+2
#pragma unroll
  for (int tt = 0; tt < NT; ++tt) {
    // wait: my stage-tt loads landed.  Steady state: the <=5 outstanding are stage(tt+1)'s
    // (FIFO).  Final iteration: no stage(tt+1) exists -> must drain fully (R7 bug).
    if (tt == NT - 1) asm volatile("s_waitcnt vmcnt(0)" ::: "memory");
    else              asm volatile("s_waitcnt vmcnt(5)" ::: "memory");
    __builtin_amdgcn_s_barrier();      // all waves' stage-tt visible; all done reading buf nx2
    __builtin_amdgcn_sched_barrier(0);
    if (tt + 2 < NT) stage(nx2, (tt + 2) * 32);
    const u16* lb = &lds[cur][0];
    bf16x8 af[4], bfr[6];
#pragma unroll
    for (int i = 0; i < 4; i++) af[i] = *(const bf16x8*)&lb[aoff[i]];
#pragma unroll
    for (int j = 0; j < 6; j++) bfr[j] = *(const bf16x8*)&lb[boff[j]];
#pragma unroll
    for (int i = 0; i < 4; i++)
#pragma unroll
      for (int j = 0; j < 6; j++) acc[i][j] = MFMA16(af[i], bfr[j], acc[i][j]);
    cur = (cur == 2) ? 0 : cur + 1;
    nx2 = (nx2 == 2) ? 0 : nx2 + 1;
  }

  // ---- epilogue ----
  float bcol[6];
#pragma unroll
  for (int j = 0; j < 6; j++) bcol[j] = bias[nb * BN + wx * 96 + j * 16 + l15];

  if constexpr (EPI == 1) {
    // proj + residual + fused LN2.  Requires gridDim.x == 1 (full 192-wide rows per block).
    __syncthreads();                        // all waves done with LDS compute buffers
    float* partS = (float*)&lds[0][0];      // [128][2]
    float* partQ = partS + 256;             // [128][2]
    float g2c[6], b2c[6];
#pragma unroll
    for (int j = 0; j < 6; j++) {
      g2c[j] = g2[wx * 96 + j * 16 + l15];
      b2c[j] = b2[wx * 96 + j * 16 + l15];
    }
    float s1a[4][4], s2a[4][4];
#pragma unroll
    for (int i = 0; i < 4; i++) {
#pragma unroll
      for (int r = 0; r < 4; r++) {
        const int lrow = wy * 64 + i * 16 + quad * 4 + r;
        const long tokoff = row2tok(mb * BM + lrow) * 192;
        float s1 = 0.f, s2 = 0.f;
#pragma unroll
        for (int j = 0; j < 6; j++) {
          const int gcol = wx * 96 + j * 16 + l15;
          float v = acc[i][j][r] + bcol[j] + resid[tokoff + gcol];
          acc[i][j][r] = v;
          s1 += v; s2 += v * v;
        }
        s1 += __shfl_xor(s1, 1); s1 += __shfl_xor(s1, 2); s1 += __shfl_xor(s1, 4); s1 += __shfl_xor(s1, 8);
        s2 += __shfl_xor(s2, 1); s2 += __shfl_xor(s2, 2); s2 += __shfl_xor(s2, 4); s2 += __shfl_xor(s2, 8);
        if (l15 == 0) { partS[lrow * 2 + wx] = s1; partQ[lrow * 2 + wx] = s2; }
        s1a[i][r] = s1; s2a[i][r] = s2;
      }
    }
    __syncthreads();
#pragma unroll
    for (int i = 0; i < 4; i++) {
#pragma unroll
      for (int r = 0; r < 4; r++) {
        const int lrow = wy * 64 + i * 16 + quad * 4 + r;
        const long grow = mb * BM + lrow;
        float ts = s1a[i][r] + partS[lrow * 2 + (wx ^ 1)];
        float tq = s2a[i][r] + partQ[lrow * 2 + (wx ^ 1)];
        float mu = ts * (1.f / 192.f);
        float rstd = rsqrtf(tq * (1.f / 192.f) - mu * mu + 1e-5f);
#pragma unroll
        for (int j = 0; j < 6; j++) {
          const int gcol = wx * 96 + j * 16 + l15;
          float v = acc[i][j][r];
          ((u16*)outp)[grow * 192 + gcol] = f2bf(v);
          xmout[grow * 192 + gcol] = f2bf((v - mu) * rstd * g2c[j] + b2c[j]);
        }
      }
    }
    return;
  }

  const float qs = (EPI == 0 && nb == 0) ? kScale : 1.f;   // fold q scaling into qkv epilogue
#pragma unroll
  for (int i = 0; i < 4; i++) {
#pragma unroll
    for (int r = 0; r < 4; r++) {
      const int grow = mb * BM + wy * 64 + i * 16 + quad * 4 + r;
      long tokoff = 0;
      if constexpr (EPI == 3) tokoff = row2tok(grow) * 192;
#pragma unroll
      for (int j = 0; j < 6; j++) {
        const int gcol = nb * BN + wx * 96 + j * 16 + l15;
        float v = acc[i][j][r] + bcol[j];
        if constexpr (EPI == 0) {
          ((u16*)outp)[(long)grow * ND + gcol] = f2bf(v * qs);
        } else if constexpr (EPI == 2) {
          ((u16*)outp)[(long)grow * ND + gcol] = f2bf(gelu_tanh(v));
        } else {
          ((float*)outp)[tokoff + gcol] = v + bf2f(x1[(long)grow * 192 + gcol]);
        }
      }
    }
  }
}

// ---- windowed MFMA attention: one block per (window, head) ----
// Q pre-scaled at qkv epilogue.  p = exp(s)*EB (no max-sub: |s| << 80), pre-normalized before PV.
__global__ __launch_bounds__(256, 3)
void attn_kernel(const u16* __restrict__ qkv, const float* __restrict__ EB, u16* __restrict__ attno) {
  __shared__ u16 uQK[17408];     // Qs[128*40] | Ks[128*40], later reused as Ps[128*136]
  __shared__ u16 Vt[32 * 136];   // V transposed [d][m]

  const int bid = blockIdx.x;
  const int wi = bid / kNH;           // global window 0..1023
  const int hh = bid - wi * kNH;      // head
  const int widx = wi & 511;          // window within image
  const int t = threadIdx.x;
  const int lane = t & 63, wv = t >> 6;
  const int quad = lane >> 4, l15 = lane & 15;

  {  // stage Q, K, V^T
    const int rr = t >> 1, half = (t & 1) * 16;
    const long base = (long)(wi * 128 + rr) * 576 + hh * 32 + half;
    uint4 q0 = *(const uint4*)(qkv + base);
    uint4 q1 = *(const uint4*)(qkv + base + 8);
    uint4 k0 = *(const uint4*)(qkv + base + 192);
    uint4 k1 = *(const uint4*)(qkv + base + 200);
    union { uint4 q[2]; u16 s[16]; } vv;
    vv.q[0] = *(const uint4*)(qkv + base + 384);
    vv.q[1] = *(const uint4*)(qkv + base + 392);
    u16* Qs = uQK;
    u16* Ks = uQK + 5120;
    *(uint4*)&Qs[rr * 40 + half] = q0;
    *(uint4*)&Qs[rr * 40 + half + 8] = q1;
    *(uint4*)&Ks[rr * 40 + half] = k0;
    *(uint4*)&Ks[rr * 40 + half + 8] = k1;
#pragma unroll
    for (int c = 0; c < 16; c++) Vt[(half + c) * 136 + rr] = vv.s[c];
  }
  __syncthreads();

  // S = Q K^T : each wave does rows [wv*32, wv*32+32) x 128 cols
  f32x4 sacc[2][8];
#pragma unroll
  for (int i = 0; i < 2; i++)
#pragma unroll
    for (int j = 0; j < 8; j++) sacc[i][j] = (f32x4){0.f, 0.f, 0.f, 0.f};
  {
    const u16* Qs = uQK;
    const u16* Ks = uQK + 5120;
    bf16x8 aq[2];
#pragma unroll
    for (int i = 0; i < 2; i++) aq[i] = *(const bf16x8*)&Qs[(wv * 32 + i * 16 + l15) * 40 + quad * 8];
    __builtin_amdgcn_s_setprio(1);
#pragma unroll
    for (int j = 0; j < 8; j++) {
      bf16x8 bk = *(const bf16x8*)&Ks[(j * 16 + l15) * 40 + quad * 8];
      sacc[0][j] = MFMA16(aq[0], bk, sacc[0][j]);
      sacc[1][j] = MFMA16(aq[1], bk, sacc[1][j]);
    }
    __builtin_amdgcn_s_setprio(0);
  }
  __syncthreads();  // all waves done with Qs/Ks; region becomes Ps

  // p = exp(s) * EB * maskbit, row-normalized, -> LDS bf16
  u16* Ps = uQK;  // [128][136]
  int ccnt[8];
#pragma unroll
  for (int j = 0; j < 8; j++) ccnt[j] = rcode(widx, j * 16 + l15);
  const float* EBh = EB + (hh << 14) + l15;
#pragma unroll
  for (int i = 0; i < 2; i++) {
#pragma unroll
    for (int r = 0; r < 4; r++) {
      int n = wv * 32 + i * 16 + quad * 4 + r;
      int rc = rcode(widx, n);
      const float* ebr = EBh + (n << 7);
      float pv[8];
      float l = 0.f;
#pragma unroll
      for (int j = 0; j < 8; j++) {
        float eb = ebr[j * 16];
        eb = (rc == ccnt[j]) ? eb : 0.f;
        float p = __expf(sacc[i][j][r]) * eb;
        pv[j] = p;
        l += p;
      }
      l += __shfl_xor(l, 1);
      l += __shfl_xor(l, 2);
      l += __shfl_xor(l, 4);
      l += __shfl_xor(l, 8);
      float rl = 1.f / l;
#pragma unroll
      for (int j = 0; j < 8; j++) Ps[n * 136 + j * 16 + l15] = f2bf(pv[j] * rl);
    }
  }
  __syncthreads();

  // O = P V : rows [wv*32, +32) x 32 cols
  f32x4 oacc[2][2];
#pragma unroll
  for (int i = 0; i < 2; i++)
#pragma unroll
    for (int j = 0; j < 2; j++) oacc[i][j] = (f32x4){0.f, 0.f, 0.f, 0.f};
  __builtin_amdgcn_s_setprio(1);
#pragma unroll
  for (int mc = 0; mc < 4; mc++) {
    bf16x8 ap[2], bv[2];
#pragma unroll
    for (int i = 0; i < 2; i++) ap[i] = *(const bf16x8*)&Ps[(wv * 32 + i * 16 + l15) * 136 + mc * 32 + quad * 8];
#pragma unroll
    for (int jj = 0; jj < 2; jj++) bv[jj] = *(const bf16x8*)&Vt[(jj * 16 + l15) * 136 + mc * 32 + quad * 8];
#pragma unroll
    for (int i = 0; i < 2; i++)
#pragma unroll
      for (int jj = 0; jj < 2; jj++) oacc[i][jj] = MFMA16(ap[i], bv[jj], oacc[i][jj]);
  }
  __builtin_amdgcn_s_setprio(0);
#pragma unroll
  for (int i = 0; i < 2; i++) {
#pragma unroll
    for (int jj = 0; jj < 2; jj++) {
#pragma unroll
      for (int r = 0; r < 4; r++) {
        int n = wv * 32 + i * 16 + quad * 4 + r;
        int d = jj * 16 + l15;
        attno[(long)(wi * 128 + n) * 192 + hh * 32 + d] = f2bf(oacc[i][jj][r]);
      }
    }
  }
}

extern "C" void kernel_launch(void* const* d_in, const int* in_sizes, int n_in,
                              void* d_out, int out_size, void* d_ws, size_t ws_size,
                              hipStream_t stream) {
  const float* x      = (const float*)d_in[0];
  const float* n1g    = (const float*)d_in[1];
  const float* n1b    = (const float*)d_in[2];
  const float* qkv_w  = (const float*)d_in[3];
  const float* qkv_b  = (const float*)d_in[4];
  const float* rpb    = (const float*)d_in[5];
  const float* proj_w = (const float*)d_in[6];
  const float* proj_b = (const float*)d_in[7];
  const float* n2g    = (const float*)d_in[8];
  const float* n2b    = (const float*)d_in[9];
  const float* fc1_w  = (const float*)d_in[10];
  const float* fc1_b  = (const float*)d_in[11];
  const float* fc2_w  = (const float*)d_in[12];
  const float* fc2_b  = (const float*)d_in[13];

  char* ws = (char*)d_ws;
  size_t off = 0;
  auto alloc = [&](size_t bytes) -> void* {
    void* p = ws + off;
    off += (bytes + 255) & ~(size_t)255;
    return p;
  };
  // lifetimes: xw: LN1out -> qkv; reused as attno (attn -> proj), reused as xm (LN2 -> fc1)
  //            qkvb: qkv (576 cols) -> attn; reused as fc1out (768 cols) -> fc2
  //            x1: residual stream bf16 in WINDOW order (proj out) -> fc2 epilogue.
  u16* WtQKV  = (u16*)alloc((size_t)110592 * 2);
  u16* WtPROJ = (u16*)alloc((size_t)36864 * 2);
  u16* WtFC1  = (u16*)alloc((size_t)147456 * 2);
  u16* WtFC2  = (u16*)alloc((size_t)147456 * 2);
  float* EB   = (float*)alloc((size_t)98304 * 4);   // exp(rel-pos-bias) [6][128][128]
  u16* xw     = (u16*)alloc((size_t)kTok * 192 * 2);
  u16* qkvb   = (u16*)alloc((size_t)kTok * 768 * 2);
  u16* x1     = (u16*)alloc((size_t)kTok * 192 * 2);
  u16* attno  = xw;
  u16* xm     = xw;

  transpose_kernel<<<(110592 + 255) / 256, 256, 0, stream>>>(qkv_w, WtQKV, 192, 576);
  transpose_kernel<<<(36864 + 255) / 256, 256, 0, stream>>>(proj_w, WtPROJ, 192, 192);
  transpose_kernel<<<(147456 + 255) / 256, 256, 0, stream>>>(fc1_w, WtFC1, 192, 768);
  transpose_kernel<<<(147456 + 255) / 256, 256, 0, stream>>>(fc2_w, WtFC2, 768, 192);
  ebias_kernel<<<98304 / 256, 256, 0, stream>>>(rpb, EB);

  ln1_kernel<<<kTok / 4, 256, 0, stream>>>(x, n1g, n1b, xw);
  // QKV: N=576 = 3 x 192 exact; q columns (nb==0) pre-scaled
  gemm_kernel<192, 576, 0><<<dim3(3, kTok / 128), 256, 0, stream>>>(xw, WtQKV, qkv_b, qkvb, nullptr, nullptr, nullptr, nullptr, nullptr);
  attn_kernel<<<1024 * kNH, 256, 0, stream>>>(qkvb, EB, attno);
  // proj: N=192, nb=1; gather resid (token order), write x1 + fused-LN2 xm (window order)
  gemm_kernel<192, 192, 1><<<dim3(1, kTok / 128), 256, 0, stream>>>(attno, WtPROJ, proj_b, x1, x, nullptr, n2g, n2b, xm);
  // fc1: N=768 = 4 x 192 exact
  gemm_kernel<192, 768, 2><<<dim3(4, kTok / 128), 256, 0, stream>>>(xm, WtFC1, fc1_b, qkvb, nullptr, nullptr, nullptr, nullptr, nullptr);
  // fc2: N=192, nb=1; scatter final fp32 out to token order
  gemm_kernel<768, 192, 3><<<dim3(1, kTok / 128), 256, 0, stream>>>(qkvb, WtFC2, fc2_b, d_out, nullptr, x1, nullptr, nullptr, nullptr);
}